// Round 1
// 5563.318 us; speedup vs baseline: 1.1007x; 1.1007x over previous
//
#include <hip/hip_runtime.h>

#define B_ 64
#define S_ 512
#define I_ 512
#define H_ 1024
#define NBLK 128
#define OFF_H 33554432            // B_*S_*H_
#define OFF_C (33554432 + 65536)  // + B_*H_

typedef short bf16x8 __attribute__((ext_vector_type(8)));
typedef unsigned short u16x8 __attribute__((ext_vector_type(8)));
typedef float f32x4 __attribute__((ext_vector_type(4)));
typedef unsigned long long ull;

__device__ __forceinline__ unsigned short f2b(float f) {
  unsigned u = __float_as_uint(f);
  u += 0x7fffu + ((u >> 16) & 1u);   // RNE
  return (unsigned short)(u >> 16);
}
__device__ __forceinline__ float sigf(float x) { return 1.0f / (1.0f + __expf(-x)); }
__device__ __forceinline__ float tanh_(float x) { return 2.0f / (1.0f + __expf(-2.0f * x)) - 1.0f; }

// ---------- preamble: x -> bf16 ----------
__global__ __launch_bounds__(256) void k_cvt_x(const float* __restrict__ x,
                                               unsigned short* __restrict__ x16) {
  long long i = ((long long)blockIdx.x * 256 + threadIdx.x) * 8;
  float4 a = *(const float4*)(x + i);
  float4 b = *(const float4*)(x + i + 4);
  u16x8 o;
  o[0] = f2b(a.x); o[1] = f2b(a.y); o[2] = f2b(a.z); o[3] = f2b(a.w);
  o[4] = f2b(b.x); o[5] = f2b(b.y); o[6] = f2b(b.z); o[7] = f2b(b.w);
  *(u16x8*)(x16 + i) = o;
}

// ---------- preamble: W_x -> fragment-ordered bf16 [g][ct2][kc16][lane][8] ----------
__global__ __launch_bounds__(256) void k_wx(const float* __restrict__ Wx,
                                            unsigned short* __restrict__ wxf) {
  int gid = blockIdx.x * 256 + threadIdx.x;
  int lane = gid & 63, kc = (gid >> 6) & 15, ct = (gid >> 10) & 1, g = gid >> 11;
  int c = lane & 15, q = lane >> 4;
  int col = (ct * 2 + (c >> 3)) * H_ + g * 8 + (c & 7);  // gate-major column mapping
  int k0 = kc * 32 + q * 8;
  u16x8 o;
#pragma unroll
  for (int j = 0; j < 8; ++j) o[j] = f2b(Wx[(long long)(k0 + j) * (4 * H_) + col]);
  *(u16x8*)(wxf + (long long)gid * 8) = o;
}

// ---------- preamble: W_h -> fragment-ordered bf16 [g][ct2][kc32][lane][8] ----------
__global__ __launch_bounds__(256) void k_wh(const float* __restrict__ Wh,
                                            unsigned short* __restrict__ whf) {
  int gid = blockIdx.x * 256 + threadIdx.x;
  int lane = gid & 63, kc = (gid >> 6) & 31, ct = (gid >> 11) & 1, g = gid >> 12;
  int c = lane & 15, q = lane >> 4;
  int col = (ct * 2 + (c >> 3)) * H_ + g * 8 + (c & 7);
  int k0 = kc * 32 + q * 8;
  u16x8 o;
#pragma unroll
  for (int j = 0; j < 8; ++j) o[j] = f2b(Wh[(long long)(k0 + j) * (4 * H_) + col]);
  *(u16x8*)(whf + (long long)gid * 8) = o;
}

// ---------- persistent scan kernel: 128 blocks x 256 threads ----------
// Barrier-free dataflow: h for step t lives in its own write-once region
// (hbuf + t*B_*H_). Granule validity = all-u32-nonzero (h bf16 +0.0 is
// remapped to -0.0, numerically exact). Per-wave relaxed hint flags
// (flags[wave*128 + g] = steps completed) gate cheap re-polls; data is
// always validated, so no fences / drains / __syncthreads are needed in
// the scan loop. Waves free-run; run-ahead absorbs jitter (no max-over-
// 128-blocks amplification).
__global__ __launch_bounds__(256, 1) void k_scan(
    const unsigned short* __restrict__ x16, const unsigned short* __restrict__ wxf,
    const unsigned short* __restrict__ whf, const float* __restrict__ bias,
    unsigned short* __restrict__ hbuf, unsigned* __restrict__ flags,
    float* __restrict__ out) {
  __shared__ unsigned short ldsWh[2 * 32 * 64 * 8];  // 64 KB, fragment order
  __shared__ unsigned short ldsWx[2 * 16 * 64 * 8];  // 32 KB, fragment order
  const int tid = threadIdx.x, g = blockIdx.x;

  for (int i = tid; i < 4096; i += 256)
    ((u16x8*)ldsWh)[i] = ((const u16x8*)(whf + (long long)g * 32768))[i];
  for (int i = tid; i < 2048; i += 256)
    ((u16x8*)ldsWx)[i] = ((const u16x8*)(wxf + (long long)g * 16384))[i];
  __syncthreads();  // the ONLY barrier; LDS is read-only afterwards

  const int wave = tid >> 6, lane = tid & 63;
  const int c = lane & 15, q = lane >> 4;
  const int rowA = wave * 16 + c;   // A-operand batch row
  const int kofs = q * 8;
  const int j = 8 * g + (c & 7);    // hidden index owned (lanes c<8)
  const float bias0 = bias[(c >> 3) * H_ + j];        // i (c<8) / f (c>=8)
  const float bias1 = bias[(2 + (c >> 3)) * H_ + j];  // g / o
  const int rowD = wave * 16 + q * 4;
  f32x4 cst = {0.f, 0.f, 0.f, 0.f};

  const unsigned short* xrow = x16 + (long long)rowA * (S_ * I_) + kofs;
  const ull* hrow = (const ull*)(hbuf + (long long)rowA * H_ + kofs);
  const unsigned* fl = flags + wave * 128;  // this wave's hint row

  for (int t = 0; t < S_; ++t) {
    f32x4 a0 = {bias0, bias0, bias0, bias0};
    f32x4 a1 = {bias1, bias1, bias1, bias1};

    // ---- x-part: independent of h_t; overlaps peers' h_t propagation ----
    const unsigned short* xp = xrow + t * I_;
#pragma unroll
    for (int kc = 0; kc < 16; ++kc) {
      bf16x8 av = *(const bf16x8*)(xp + kc * 32);
      bf16x8 b0 = *(const bf16x8*)(ldsWx + kc * 512 + lane * 8);
      bf16x8 b1 = *(const bf16x8*)(ldsWx + (16 + kc) * 512 + lane * 8);
      a0 = __builtin_amdgcn_mfma_f32_16x16x32_bf16(av, b0, a0, 0, 0, 0);
      a1 = __builtin_amdgcn_mfma_f32_16x16x32_bf16(av, b1, a1, 0, 0, 0);
    }

    // ---- h-part: self-validating dataflow consumption (skip t=0: h_0=0) ----
    if (t > 0) {
      const ull* hq = hrow + (long long)t * 16384;  // region for h_t (u64 units)
      unsigned done = 0u;

      auto sweep = [&](unsigned todo) {
        ull hlo[32], hhi[32];
#pragma unroll
        for (int kc = 0; kc < 32; ++kc) {
          if (todo & (1u << kc)) {
            hlo[kc] = __hip_atomic_load(hq + kc * 8, __ATOMIC_RELAXED,
                                        __HIP_MEMORY_SCOPE_AGENT);
            hhi[kc] = __hip_atomic_load(hq + kc * 8 + 1, __ATOMIC_RELAXED,
                                        __HIP_MEMORY_SCOPE_AGENT);
          }
        }
#pragma unroll
        for (int kc = 0; kc < 32; ++kc) {
          if (todo & (1u << kc)) {
            ull l0 = hlo[kc], l1 = hhi[kc];
            int ok = ((unsigned)l0 != 0u) && ((unsigned)(l0 >> 32) != 0u) &&
                     ((unsigned)l1 != 0u) && ((unsigned)(l1 >> 32) != 0u);
            if (__all(ok)) {
              union { ull qw[2]; bf16x8 v; } u;
              u.qw[0] = l0; u.qw[1] = l1;
              bf16x8 av = u.v;
              bf16x8 b0 = *(const bf16x8*)(ldsWh + kc * 512 + lane * 8);
              bf16x8 b1 = *(const bf16x8*)(ldsWh + (32 + kc) * 512 + lane * 8);
              a0 = __builtin_amdgcn_mfma_f32_16x16x32_bf16(av, b0, a0, 0, 0, 0);
              a1 = __builtin_amdgcn_mfma_f32_16x16x32_bf16(av, b1, a1, 0, 0, 0);
              done |= 1u << kc;
            }
          }
        }
      };

      // speculative first sweep: zero added latency when peers are ahead
      sweep(0xffffffffu);

      // laggards: thin flag-hint polling (2 cache lines), then gated reload
      while (done != 0xffffffffu) {
        const unsigned tgt = (unsigned)t;
        unsigned f0 = __hip_atomic_load(fl + lane, __ATOMIC_RELAXED,
                                        __HIP_MEMORY_SCOPE_AGENT);
        unsigned f1 = __hip_atomic_load(fl + 64 + lane, __ATOMIC_RELAXED,
                                        __HIP_MEMORY_SCOPE_AGENT);
        ull m0 = __ballot(f0 >= tgt);   // producers 0..63  -> chunks 0..15
        ull m1 = __ballot(f1 >= tgt);   // producers 64..127 -> chunks 16..31
        m0 &= (m0 >> 1) & (m0 >> 2) & (m0 >> 3);  // bit 4k = chunk k's 4 producers done
        m1 &= (m1 >> 1) & (m1 >> 2) & (m1 >> 3);
        unsigned hint = 0;
#pragma unroll
        for (int i = 0; i < 16; ++i) {
          hint |= (unsigned)((m0 >> (4 * i)) & 1ull) << i;
          hint |= (unsigned)((m1 >> (4 * i)) & 1ull) << (16 + i);
        }
        unsigned todo = hint & ~done;
        if (todo) sweep(todo);
      }
    }

    // ---- elementwise LSTM update (lane c pairs with lane c+8) ----
    f32x4 h4;
#pragma unroll
    for (int r = 0; r < 4; ++r) {
      float fg = __shfl_xor(a0[r], 8, 64);  // f at lanes c<8
      float og = __shfl_xor(a1[r], 8, 64);  // o at lanes c<8
      float iv = sigf(a0[r]);
      float fv = sigf(fg);
      float gv = tanh_(a1[r]);
      float ov = sigf(og);
      float cv = fv * cst[r] + iv * gv;
      cst[r] = cv;
      h4[r] = ov * tanh_(cv);
    }

    // ---- publish h_{t+1} into its fresh region (no drain, no barrier) ----
    if (c < 8) {
      unsigned short* hw = hbuf + (long long)(t + 1) * (B_ * H_);
#pragma unroll
      for (int r = 0; r < 4; ++r) {
        int b = rowD + r;
        unsigned short hb = f2b(h4[r]);
        if (hb == 0) hb = 0x8000;  // +0.0 -> -0.0: exact, keeps token nonzero
        unsigned pv = (unsigned)__shfl_xor((int)hb, 1, 64) & 0xffffu;
        if ((c & 1) == 0) {
          __hip_atomic_store((unsigned*)(hw + b * H_ + j),
                             ((unsigned)hb) | (pv << 16), __ATOMIC_RELAXED,
                             __HIP_MEMORY_SCOPE_AGENT);
        }
      }
    }
    // per-wave hint flag: relaxed, issued after h stores (program order);
    // consumers validate data, so no vmcnt drain is required here.
    if (lane == 0)
      __hip_atomic_store((unsigned*)(flags + wave * 128 + g), (unsigned)(t + 1),
                         __ATOMIC_RELAXED, __HIP_MEMORY_SCOPE_AGENT);

    // ---- out f32 stores AFTER publish: fully off the critical path ----
    if (c < 8) {
#pragma unroll
      for (int r = 0; r < 4; ++r) {
        int b = rowD + r;
        out[((long long)b * S_ + t) * H_ + j] = h4[r];
      }
      if (t == S_ - 1) {
#pragma unroll
        for (int r = 0; r < 4; ++r) {
          int b = rowD + r;
          out[OFF_H + b * H_ + j] = h4[r];
          out[OFF_C + b * H_ + j] = cst[r];
        }
      }
    }
  }
}

extern "C" void kernel_launch(void* const* d_in, const int* in_sizes, int n_in,
                              void* d_out, int out_size, void* d_ws, size_t ws_size,
                              hipStream_t stream) {
  const float* x = (const float*)d_in[0];
  const float* Wx = (const float*)d_in[1];
  const float* Wh = (const float*)d_in[2];
  const float* bias = (const float*)d_in[3];
  float* out = (float*)d_out;
  char* ws = (char*)d_ws;

  // ws layout (bytes):
  //   [0, 2048)                 flags[4*128] (per-wave producer step counters)
  //   [4096, 67244032)          h regions, bf16 [513][64][1024] (write-once per step)
  //   [67244032, 100798464)     x16 bf16 (33.5 MB)
  //   [100798464, 104992768)    wxf fragment-ordered W_x bf16 (4 MB)
  //   [104992768, 113381376)    whf fragment-ordered W_h bf16 (8 MB)  total ~113.4 MB
  unsigned* flags = (unsigned*)ws;
  unsigned short* hbuf = (unsigned short*)(ws + 4096);
  unsigned short* x16 = (unsigned short*)(ws + 67244032);
  unsigned short* wxf = (unsigned short*)(ws + 100798464);
  unsigned short* whf = (unsigned short*)(ws + 104992768);

  // zero flags + all h regions (validity tokens rely on zero-init each run)
  hipMemsetAsync(ws, 0, 67244032, stream);
  hipLaunchKernelGGL(k_cvt_x, dim3(8192), dim3(256), 0, stream, x, x16);
  hipLaunchKernelGGL(k_wx, dim3(1024), dim3(256), 0, stream, Wx, wxf);
  hipLaunchKernelGGL(k_wh, dim3(2048), dim3(256), 0, stream, Wh, whf);
  hipLaunchKernelGGL(k_scan, dim3(NBLK), dim3(256), 0, stream, x16, wxf, whf, bias,
                     hbuf, flags, out);
  (void)in_sizes; (void)n_in; (void)out_size; (void)ws_size;
}